// Round 16
// baseline (111.190 us; speedup 1.0000x reference)
//
#include <hip/hip_runtime.h>
#include <string.h>
#include <math.h>

#define NCRD 4096
#define NROW 8192
#define MT   32            // rows per block -> 256 blocks (1/CU)
#define WG_U4 94208        // total prepped weight size in uint4 (1.44 MB)

typedef __attribute__((ext_vector_type(8)))  _Float16 half8;
typedef __attribute__((ext_vector_type(16))) float f32x16;
typedef __attribute__((ext_vector_type(4)))  int   i32x4;

static __device__ __forceinline__ float sinrev(float t){ return __builtin_amdgcn_sinf(__builtin_amdgcn_fractf(t)); }
static __device__ __forceinline__ float cosrev(float t){ return __builtin_amdgcn_cosf(__builtin_amdgcn_fractf(t)); }
static __device__ __forceinline__ unsigned short f2h(float f){   // RNE f32->fp16
    _Float16 h = (_Float16)f;
    unsigned short u; memcpy(&u, &h, 2); return u;
}

// RNE float -> OCP e4m3fn bits (finite inputs, |v| <= 448). Self-contained.
static __device__ unsigned char f2e4m3(float v){
    unsigned int s = (__float_as_uint(v) >> 24) & 0x80;
    float a = fabsf(v);
    if (a >= 448.f) return (unsigned char)(s | 0x7e);
    int e; frexpf(a, &e); e -= 1;                  // a = 1.x * 2^e
    if (e < -6) e = -6;                            // denormal regime
    float step = exp2f((float)(e - 3));
    float q = rintf(a / step) * step;              // RNE onto 3-bit grid
    if (q <= 0.f) return (unsigned char)s;
    int e2; float m = frexpf(q, &e2);              // m in [0.5,1)
    int E = e2 + 6;
    unsigned int bits;
    if (E >= 1) bits = ((unsigned)E << 3) | ((unsigned)rintf(m*16.f) - 8u);
    else        bits = (unsigned)rintf(q * 512.f); // denormal: q = D*2^-9
    return (unsigned char)(s | bits);
}

// Scheduler-opaque 16B global load (R12/R13 lesson: consume-copy slots first).
static __device__ __forceinline__ i32x4 gload16(const uint4* p){
    i32x4 r;
    asm volatile("global_load_dwordx4 %0, %1, off" : "=v"(r) : "v"(p) : "memory");
    return r;
}
static __device__ __forceinline__ void vmwaitK(int K, i32x4& a, i32x4& b){
    if (K >= 16)      asm volatile("s_waitcnt vmcnt(16)" : "+v"(a), "+v"(b));
    else if (K >= 14) asm volatile("s_waitcnt vmcnt(14)" : "+v"(a), "+v"(b));
    else if (K >= 12) asm volatile("s_waitcnt vmcnt(12)" : "+v"(a), "+v"(b));
    else if (K >= 10) asm volatile("s_waitcnt vmcnt(10)" : "+v"(a), "+v"(b));
    else if (K >= 8)  asm volatile("s_waitcnt vmcnt(8)"  : "+v"(a), "+v"(b));
    else if (K >= 6)  asm volatile("s_waitcnt vmcnt(6)"  : "+v"(a), "+v"(b));
    else if (K >= 4)  asm volatile("s_waitcnt vmcnt(4)"  : "+v"(a), "+v"(b));
    else if (K >= 2)  asm volatile("s_waitcnt vmcnt(2)"  : "+v"(a), "+v"(b));
    else              asm volatile("s_waitcnt vmcnt(0)"  : "+v"(a), "+v"(b));
}

// fp8 e4m3 byte -> fp16 bits = value * 2^-8 (uniform, incl. denormals):
//   h = sign<<15 | (eeee mmm)<<7.  Packed two-at-a-time per dword.
static __device__ __forceinline__ void expand2(unsigned int d, unsigned int& o0, unsigned int& o1){
    o0 = ((d << 8) & 0x80008000u) | ((d << 7) & 0x3f803f80u);  // bytes 0,2
    o1 = ( d       & 0x80008000u) | ((d >> 1) & 0x3f803f80u);  // bytes 1,3
}
static __device__ __forceinline__ half8 expand_frag(unsigned int da, unsigned int db){
    unsigned int r[4];
    expand2(da, r[0], r[1]);
    expand2(db, r[2], r[3]);
    half8 h; memcpy(&h, r, 16); return h;
}

// Weight layout per sin layer (12288 u4): fp16 W part = 8 chunks (idx<8192,
// same layout as before: idx = c*1024 + wv*128 + hh*64 + lane). fp8 W3 part
// (idx2 = idx-8192 = q*1024 + wv*128 + L*64 + lane): lane's 16B = 16 fp8 of
// -512*w^3/6 at k = q*64 + L*32 + f*16 + ls*8 + jj, byte b -> f=b>>3,
// jj = (b&4)|((b&1)<<1)|((b>>1)&1)  (interleave matching expand2).
// GEMM layers: 8192 u4 fp16 W/(2pi). Runtime: fp8 decoded *2^-8, x^3 stored
// /2 -> product = (-512 w^3/6 * 2^-8) * (x^3/2) = -w^3 x^3 / 6.  Exact comp.
__constant__ int c_offs[9] = {0,12288,20480,32768,40960,53248,61440,73728,81920};

// ---- prep: one coalesced uint4 store per thread; l==9: bias+coords --------
__global__ void prep_kernel(const float* __restrict__ w0, const float* __restrict__ ws,
                            const float* __restrict__ wlast, const float* __restrict__ w1,
                            const float* __restrict__ coords, const float* __restrict__ b1,
                            uint4* __restrict__ Wg, float* __restrict__ b1s,
                            float* __restrict__ out)
{
    int l = blockIdx.x, part = blockIdx.y, t = threadIdx.x;
    const float inv2pi = 0.15915494309189535f;
    if (l == 9) {
        int base = part*256 + t;                       // 0..12287
        if (base < 1024) b1s[base] = b1[base]*inv2pi;
        for (int i = base; i < NCRD*6; i += 12288)
            out[(size_t)NROW*256 + i] = coords[i];
        return;
    }
    bool sinl = !(l & 1);
    if (!sinl && part >= 32) return;                   // gemm: 8192 u4
    const float* src;
    switch (l) {
        case 0: src = w0;          break;
        case 1: src = w1;          break;
        case 2: src = ws;          break;
        case 3: src = w1+65536;    break;
        case 4: src = ws+65536;    break;
        case 5: src = w1+2*65536;  break;
        case 6: src = ws+2*65536;  break;
        case 7: src = w1+3*65536;  break;
        default: src = wlast;      break;
    }
    int idx = part*256 + t;
    if (idx < 8192) {                       // fp16 part (W, or W/2pi for gemm)
        int c  = idx >> 10, r = idx & 1023;
        int w  = r >> 7,  r2 = r & 127;
        int hh = r2 >> 6, ln = r2 & 63;
        int col  = w*32 + (ln & 31);
        int k0   = c*32 + hh*16 + (ln >> 5)*8;
        const float* s = src + col*256 + k0;
        unsigned short h[8];
        #pragma unroll
        for (int j = 0; j < 8; ++j)
            h[j] = f2h(sinl ? s[j] : s[j]*inv2pi);
        uint4 o; memcpy(&o, h, 16);
        Wg[c_offs[l] + idx] = o;
    } else {                                 // fp8 W^3 part (sin layers only)
        int idx2 = idx - 8192;               // [0,4096)
        int q  = idx2 >> 10, r = idx2 & 1023;
        int wvp = r >> 7,  r2 = r & 127;
        int L  = r2 >> 6,  ln = r2 & 63;
        int col = wvp*32 + (ln & 31);
        int ls  = ln >> 5;
        unsigned char b8[16];
        #pragma unroll
        for (int b = 0; b < 16; ++b) {
            int f  = b >> 3;
            int jj = (b & 4) | ((b & 1) << 1) | ((b >> 1) & 1);
            int kk = q*64 + L*32 + f*16 + ls*8 + jj;
            float w = src[col*256 + kk];
            b8[b] = f2e4m3(-512.0f * w*w*w * (1.0f/6.0f));
        }
        uint4 o; memcpy(&o, b8, 16);
        Wg[c_offs[l] + idx] = o;
    }
}

// ---------------- sin layer: 8 fp16 chunks + 4 fp8 chunks ------------------
// MODE 0: write x, x^3/2 to xa.  MODE 2: final, write out.
template<int MODE>
static __device__ __forceinline__ void do_sin_layer(
    const uint4* __restrict__ wq,     // per-lane fp16 base for this layer
    float* __restrict__ outg,
    unsigned short* xa,
    int wv, int ls, int lm, int n0)
{
    constexpr int RS = 9;
    f32x16 acc = {0.f,0.f,0.f,0.f,0.f,0.f,0.f,0.f,0.f,0.f,0.f,0.f,0.f,0.f,0.f,0.f};
    i32x4 ring0[RS], ring1[RS];
    #pragma unroll
    for (int p = 0; p < 8; ++p) {     // prologue: fp16 chunks 0..7 (16 loads)
        ring0[p % RS] = gload16(wq + p*1024);
        ring1[p % RS] = gload16(wq + p*1024 + 64);
    }
    __syncthreads();
    const half8* xa8 = (const half8*)xa;
    half8 pa0[2], pa1[2];
    #pragma unroll
    for (int p = 0; p < 2; ++p) {
        pa0[p] = xa8[(p*4 + ls)*32 + lm];
        pa1[p] = xa8[(p*4 + 2 + ls)*32 + lm];
    }
    const uint4* wq8 = wq + 8192;     // fp8 region, same per-lane offset
    #pragma unroll
    for (int c = 0; c < 8; ++c) {
        if (c < 4) {                  // issue fp8 chunk c (virtual 8+c)
            ring0[(8+c) % RS] = gload16(wq8 + c*1024);
            ring1[(8+c) % RS] = gload16(wq8 + c*1024 + 64);
        }
        half8 a0 = pa0[c & 1], a1 = pa1[c & 1];   // consume-copy FIRST
        if (c + 2 < 8) {
            pa0[c & 1] = xa8[((c+2)*4 + ls)*32 + lm];
            pa1[c & 1] = xa8[((c+2)*4 + 2 + ls)*32 + lm];
        }
        vmwaitK((c < 4) ? 16 : (22 - 2*c), ring0[c % RS], ring1[c % RS]);
        half8 b0, b1v;
        { i32x4 t0 = ring0[c % RS], t1 = ring1[c % RS];
          memcpy(&b0, &t0, 16); memcpy(&b1v, &t1, 16); }
        acc = __builtin_amdgcn_mfma_f32_32x32x16_f16(a0, b0,  acc, 0,0,0);
        acc = __builtin_amdgcn_mfma_f32_32x32x16_f16(a1, b1v, acc, 0,0,0);
    }
    #pragma unroll
    for (int qc = 0; qc < 4; ++qc) {  // fp8 W^3 chunks (K=64 each)
        int v = 8 + qc;
        vmwaitK(6 - 2*qc, ring0[v % RS], ring1[v % RS]);
        i32x4 t0 = ring0[v % RS], t1 = ring1[v % RS];
        half8 f0 = expand_frag((unsigned)t0[0], (unsigned)t0[1]);
        half8 f1 = expand_frag((unsigned)t0[2], (unsigned)t0[3]);
        half8 f2 = expand_frag((unsigned)t1[0], (unsigned)t1[1]);
        half8 f3 = expand_frag((unsigned)t1[2], (unsigned)t1[3]);
        half8 a0 = xa8[(32 + qc*8 + 0 + ls)*32 + lm];
        half8 a1 = xa8[(32 + qc*8 + 2 + ls)*32 + lm];
        half8 a2 = xa8[(32 + qc*8 + 4 + ls)*32 + lm];
        half8 a3 = xa8[(32 + qc*8 + 6 + ls)*32 + lm];
        acc = __builtin_amdgcn_mfma_f32_32x32x16_f16(a0, f0, acc, 0,0,0);
        acc = __builtin_amdgcn_mfma_f32_32x32x16_f16(a1, f1, acc, 0,0,0);
        acc = __builtin_amdgcn_mfma_f32_32x32x16_f16(a2, f2, acc, 0,0,0);
        acc = __builtin_amdgcn_mfma_f32_32x32x16_f16(a3, f3, acc, 0,0,0);
    }
    __syncthreads();
    // epilogue: C/D col=lane&31, row=(reg&3)+8*(reg>>2)+4*ls (m74/m101)
    int h = wv*32 + lm;
    #pragma unroll
    for (int r = 0; r < 16; ++r) {
        float v = acc[r];
        int m = (r & 3) + 8*(r >> 2) + 4*ls;
        if (MODE == 2) {
            outg[(size_t)(n0 + m)*256 + h] = v;
        } else {
            xa[(((h>>3)     )*32 + m)*8 + (h&7)] = f2h(v);
            xa[(((h>>3) + 32)*32 + m)*8 + (h&7)] = f2h(v*v*v*0.5f);
        }
    }
}

// ---------------- gemm layer: 8 fp16 chunks, sin epilogue ------------------
static __device__ __forceinline__ void do_gemm_layer(
    const uint4* __restrict__ wq,
    const float* __restrict__ br,
    unsigned short* xa,
    int wv, int ls, int lm)
{
    constexpr int RS = 9;
    f32x16 acc = {0.f,0.f,0.f,0.f,0.f,0.f,0.f,0.f,0.f,0.f,0.f,0.f,0.f,0.f,0.f,0.f};
    i32x4 ring0[RS], ring1[RS];
    #pragma unroll
    for (int p = 0; p < 8; ++p) {
        ring0[p % RS] = gload16(wq + p*1024);
        ring1[p % RS] = gload16(wq + p*1024 + 64);
    }
    __syncthreads();
    const half8* xa8 = (const half8*)xa;
    half8 pa0[2], pa1[2];
    #pragma unroll
    for (int p = 0; p < 2; ++p) {
        pa0[p] = xa8[(p*4 + ls)*32 + lm];
        pa1[p] = xa8[(p*4 + 2 + ls)*32 + lm];
    }
    #pragma unroll
    for (int c = 0; c < 8; ++c) {
        half8 a0 = pa0[c & 1], a1 = pa1[c & 1];   // consume-copy FIRST
        if (c + 2 < 8) {
            pa0[c & 1] = xa8[((c+2)*4 + ls)*32 + lm];
            pa1[c & 1] = xa8[((c+2)*4 + 2 + ls)*32 + lm];
        }
        vmwaitK(14 - 2*c, ring0[c % RS], ring1[c % RS]);
        half8 b0, b1v;
        { i32x4 t0 = ring0[c % RS], t1 = ring1[c % RS];
          memcpy(&b0, &t0, 16); memcpy(&b1v, &t1, 16); }
        acc = __builtin_amdgcn_mfma_f32_32x32x16_f16(a0, b0,  acc, 0,0,0);
        acc = __builtin_amdgcn_mfma_f32_32x32x16_f16(a1, b1v, acc, 0,0,0);
    }
    __syncthreads();
    float bb = br[wv*32 + lm];
    int h = wv*32 + lm;
    #pragma unroll
    for (int r = 0; r < 16; ++r) {
        float s = sinrev(acc[r] + bb);   // weights pre-scaled 1/2pi
        int m = (r & 3) + 8*(r >> 2) + 4*ls;
        xa[(((h>>3)     )*32 + m)*8 + (h&7)] = f2h(s);
        xa[(((h>>3) + 32)*32 + m)*8 + (h&7)] = f2h(s*s*s*0.5f);
    }
}

// ---------------- fused MFMA network kernel --------------------------------
__global__ __launch_bounds__(512, 2)
void net_kernel(const float* __restrict__ coords, const float* __restrict__ Bm,
                const uint4* __restrict__ Wg, const float* __restrict__ b1s,
                float* __restrict__ out)
{
    __shared__ unsigned short xa[64*32*8];    // 32KB activations [kb][m][k%8]
    __shared__ float cb[MT*3];
    __shared__ float bl[384];

    int tid = threadIdx.x, lane = tid & 63, wv = tid >> 6;   // wv 0..7
    int ls = (lane >> 5) & 1, lm = lane & 31;
    int n0 = blockIdx.x * MT;

    // ---- fourier features + x^3/2 -> xa ----
    for (int i = tid; i < MT*3; i += 512) {
        int r = i/3, d = i - 3*r, nv = n0 + r;
        cb[i] = (nv < NCRD) ? coords[nv*6 + d] : coords[(nv-NCRD)*6 + 3 + d];
    }
    for (int i = tid; i < 384; i += 512) bl[i] = Bm[i];
    __syncthreads();
    {
        int m = tid & 31, colb = (tid >> 5) * 16;
        float c0 = cb[m*3], c1 = cb[m*3+1], c2 = cb[m*3+2];
        unsigned short tmp[2][16];
        #pragma unroll
        for (int j = 0; j < 16; ++j) {
            int col = colb + j, f = col & 127;
            float p = c0*bl[f] + c1*bl[128+f] + c2*bl[256+f];   // 2pi cancels
            float s = (col < 128) ? sinrev(p) : cosrev(p);
            tmp[0][j] = f2h(s); tmp[1][j] = f2h(s*s*s*0.5f);
        }
        #pragma unroll
        for (int pp = 0; pp < 2; ++pp)
            #pragma unroll
            for (int g = 0; g < 2; ++g) {
                uint4 v; memcpy(&v, &tmp[pp][g*8], 16);
                *(uint4*)&xa[((pp*32 + (colb>>3) + g)*32 + m)*8] = v;
            }
    }
    // (each layer's entry barrier orders xa writes before reads)

    int wl = wv*128 + lane;
    do_sin_layer<0>(Wg +     0 + wl, nullptr, xa, wv, ls, lm, n0);
    do_gemm_layer  (Wg + 12288 + wl, b1s + 0,   xa, wv, ls, lm);
    do_sin_layer<0>(Wg + 20480 + wl, nullptr, xa, wv, ls, lm, n0);
    do_gemm_layer  (Wg + 32768 + wl, b1s + 256, xa, wv, ls, lm);
    do_sin_layer<0>(Wg + 40960 + wl, nullptr, xa, wv, ls, lm, n0);
    do_gemm_layer  (Wg + 53248 + wl, b1s + 512, xa, wv, ls, lm);
    do_sin_layer<0>(Wg + 61440 + wl, nullptr, xa, wv, ls, lm, n0);
    do_gemm_layer  (Wg + 73728 + wl, b1s + 768, xa, wv, ls, lm);
    do_sin_layer<2>(Wg + 81920 + wl, out,     xa, wv, ls, lm, n0);
}

// ---------------- launch ---------------------------------------------------
extern "C" void kernel_launch(void* const* d_in, const int* in_sizes, int n_in,
                              void* d_out, int out_size, void* d_ws, size_t ws_size,
                              hipStream_t stream)
{
    const float* coords = (const float*)d_in[0];
    const float* Bm     = (const float*)d_in[1];
    const float* w0     = (const float*)d_in[2];
    const float* ws     = (const float*)d_in[3];
    const float* wlast  = (const float*)d_in[4];
    const float* w1     = (const float*)d_in[5];
    const float* b1     = (const float*)d_in[6];
    float* out = (float*)d_out;

    uint4* Wg  = (uint4*)d_ws;                                   // 1.44 MB
    float* b1s = (float*)((char*)d_ws + (size_t)WG_U4*16);       // 4 KB fp32

    dim3 pg(10, 48);
    prep_kernel<<<pg, 256, 0, stream>>>(w0, ws, wlast, w1, coords, b1, Wg, b1s, out);
    net_kernel<<<NROW/MT, 512, 0, stream>>>(coords, Bm, Wg, b1s, out);
}